// Round 2
// baseline (261.693 us; speedup 1.0000x reference)
//
#include <hip/hip_runtime.h>
#include <math.h>

#define BSZ 8
#define DDIM 512
#define NND 2048
#define EE 8
#define LLH 64
#define NEDGE 524288
#define BNN 16384          // BSZ*NND
#define ETOT 540672        // NEDGE + BNN
#define OCC 1536           // 3*EE*LLH
#define FDIM 49152         // NND*3*EE
#define DQ 16384           // NND*EE

__device__ inline void atomicMaxF(float* addr, float v) {
    if (v >= 0.f) atomicMax((int*)addr, __float_as_int(v));
    else atomicMin((unsigned int*)addr, (unsigned int)__float_as_int(v));
}

// ---- 1. skeleton = latent @ W_dense + b_dense -> [8, 2048] ----
__global__ __launch_bounds__(256) void k_dense(const float* __restrict__ latent,
                                               const float* __restrict__ Wd,
                                               const float* __restrict__ bd,
                                               float* __restrict__ sk) {
    __shared__ float lat[BSZ * DDIM];   // 16 KB
    int tid = threadIdx.x;
    for (int i = tid; i < BSZ * DDIM; i += 256) lat[i] = latent[i];
    __syncthreads();
    int n = blockIdx.x * 32 + (tid & 31);
    int b = tid >> 5;
    float acc = 0.f;
    for (int d = 0; d < DDIM; ++d) acc += lat[b * DDIM + d] * Wd[d * NND + n];
    sk[b * NND + n] = acc + bd[n];
}

// ---- 2. conv1d(K=3, Cin=1, Cout=8, SAME) -> x [16384, 8] ----
__global__ void k_conv1(const float* __restrict__ sk, const float* __restrict__ w1,
                        const float* __restrict__ b1, float* __restrict__ xb) {
    int bn = blockIdx.x * 256 + threadIdx.x;
    if (bn >= BNN) return;
    int n = bn & (NND - 1);
    float sm = (n > 0) ? sk[bn - 1] : 0.f;
    float s0 = sk[bn];
    float sp = (n < NND - 1) ? sk[bn + 1] : 0.f;
    #pragma unroll
    for (int e = 0; e < EE; ++e)
        xb[bn * EE + e] = sm * w1[e] + s0 * w1[EE + e] + sp * w1[2 * EE + e] + b1[e];
}

// ---- 3. GAT Q/K/V projections + per-call init of reduction buffers ----
__global__ void k_gatqkv(const float* __restrict__ xb,
                         const float* __restrict__ Wq, const float* __restrict__ bq,
                         const float* __restrict__ Wk, const float* __restrict__ bk,
                         const float* __restrict__ Wv, const float* __restrict__ gbias,
                         float* __restrict__ Qg, float* __restrict__ Kg,
                         float* __restrict__ Vg, float* __restrict__ hg,
                         float* __restrict__ smax, float* __restrict__ ssum,
                         float* __restrict__ Sb) {
    int i = blockIdx.x * 256 + threadIdx.x;
    if (i >= BNN) return;
    float xr[EE];
    #pragma unroll
    for (int c = 0; c < EE; ++c) xr[c] = xb[i * EE + c];
    #pragma unroll
    for (int j = 0; j < EE; ++j) {
        float q = bq[j], k = bk[j], v = 0.f;
        #pragma unroll
        for (int c = 0; c < EE; ++c) {
            q += xr[c] * Wq[c * EE + j];
            k += xr[c] * Wk[c * EE + j];
            v += xr[c] * Wv[c * EE + j];
        }
        Qg[i * EE + j] = (q >= 0.f) ? q : 0.2f * q;
        Kg[i * EE + j] = (k >= 0.f) ? k : 0.2f * k;
        Vg[i * EE + j] = v;
        hg[i * EE + j] = gbias[j];   // aggregate lands on top of bias
    }
    smax[i] = -INFINITY;
    ssum[i] = 0.f;
    Sb[2 * i] = 0.f;
    Sb[2 * i + 1] = 0.f;
}

// ---- 4. edge scores + segment max ----
__global__ void k_escore(const int* __restrict__ ei, const float* __restrict__ Qg,
                         const float* __restrict__ Kg, float* __restrict__ sc,
                         float* __restrict__ smax) {
    int e = blockIdx.x * 256 + threadIdx.x;
    if (e >= ETOT) return;
    int r, c;
    if (e < NEDGE) { r = ei[e]; c = ei[NEDGE + e]; } else { r = c = e - NEDGE; }
    const float4* Q4 = (const float4*)(Qg + r * EE);
    const float4* K4 = (const float4*)(Kg + c * EE);
    float4 qa = Q4[0], qb2 = Q4[1], ka = K4[0], kb2 = K4[1];
    float s = qa.x * ka.x + qa.y * ka.y + qa.z * ka.z + qa.w * ka.w
            + qb2.x * kb2.x + qb2.y * kb2.y + qb2.z * kb2.z + qb2.w * kb2.w;
    sc[e] = s;
    atomicMaxF(smax + r, s);
}

// ---- 5. exp + segment sum ----
__global__ void k_eexp(const int* __restrict__ ei, const float* __restrict__ smax,
                       float* __restrict__ sc, float* __restrict__ ssum) {
    int e = blockIdx.x * 256 + threadIdx.x;
    if (e >= ETOT) return;
    int r = (e < NEDGE) ? ei[e] : e - NEDGE;
    float ex = __expf(sc[e] - smax[r]);
    sc[e] = ex;
    atomicAdd(ssum + r, ex);
}

// ---- 6. alpha * V scatter-aggregate ----
__global__ void k_eaggr(const int* __restrict__ ei, const float* __restrict__ sc,
                        const float* __restrict__ ssum, const float* __restrict__ Vg,
                        float* __restrict__ hg) {
    long long t = (long long)blockIdx.x * 256 + threadIdx.x;
    if (t >= (long long)ETOT * EE) return;
    int e = (int)(t >> 3), j = (int)(t & 7);
    int r, c;
    if (e < NEDGE) { r = ei[e]; c = ei[NEDGE + e]; } else { r = c = e - NEDGE; }
    float alpha = sc[e] / ssum[r];
    atomicAdd(hg + r * EE + j, alpha * Vg[c * EE + j]);
}

// ---- 7. qkv conv (K=3, Cin=8, Cout=1536) written transposed into Fl[b][l][n*24+c] ----
__global__ __launch_bounds__(256) void k_qkvconv(const float* __restrict__ hg,
                                                 const float* __restrict__ qw,
                                                 const float* __restrict__ qb,
                                                 float* __restrict__ Fl) {
    int o = blockIdx.x * 256 + threadIdx.x;   // gridDim.x = 6
    int n0 = blockIdx.y * 32;                 // gridDim.y = 64
    int b = blockIdx.z;                       // gridDim.z = 8
    __shared__ float g[34][EE];
    for (int i = threadIdx.x; i < 34 * EE; i += 256) {
        int nn = n0 - 1 + i / EE;
        g[i / EE][i % EE] = (nn >= 0 && nn < NND) ? hg[(b * NND + nn) * EE + (i % EE)] : 0.f;
    }
    __syncthreads();
    float w24[24];
    #pragma unroll
    for (int kk = 0; kk < 24; ++kk) w24[kk] = qw[kk * OCC + o];
    float bias = qb[o];
    int l = o / 24, c2 = o % 24;
    float* dst = Fl + ((size_t)b * LLH + l) * FDIM + c2;
    for (int nn = 0; nn < 32; ++nn) {
        float acc = bias;
        #pragma unroll
        for (int kk = 0; kk < 24; ++kk)
            acc += g[nn + (kk >> 3)][kk & 7] * w24[kk];
        dst[(size_t)(n0 + nn) * 24] = acc;
    }
}

// ---- 8. S = q @ k^T (partial over d-chunks, atomic reduce) ----
__global__ __launch_bounds__(256) void k_attnS(const float* __restrict__ Fl,
                                               float* __restrict__ Sb) {
    int b = blockIdx.y;
    int d0 = blockIdx.x * 256;
    __shared__ float qs[64][65], ks[64][65];
    int tid = threadIdx.x;
    int tq = tid >> 4, sq = tid & 15;
    float acc[4][4] = {};
    const float* qbase = Fl + (size_t)b * LLH * FDIM + d0;            // q third
    const float* kbase = Fl + (size_t)b * LLH * FDIM + 2 * DQ + d0;   // k third
    for (int dd = 0; dd < 256; dd += 64) {
        for (int i = tid; i < 64 * 64; i += 256) {
            int t = i >> 6, d = i & 63;
            qs[t][d] = qbase[(size_t)t * FDIM + dd + d];
            ks[t][d] = kbase[(size_t)t * FDIM + dd + d];
        }
        __syncthreads();
        for (int d = 0; d < 64; ++d) {
            float qv[4], kv[4];
            #pragma unroll
            for (int u = 0; u < 4; ++u) { qv[u] = qs[tq * 4 + u][d]; kv[u] = ks[sq * 4 + u][d]; }
            #pragma unroll
            for (int u = 0; u < 4; ++u)
                #pragma unroll
                for (int w = 0; w < 4; ++w)
                    acc[u][w] += qv[u] * kv[w];
        }
        __syncthreads();
    }
    float* S = Sb + (size_t)b * LLH * LLH;
    #pragma unroll
    for (int u = 0; u < 4; ++u)
        #pragma unroll
        for (int w = 0; w < 4; ++w)
            atomicAdd(S + (tq * 4 + u) * LLH + sq * 4 + w, acc[u][w]);
}

// ---- 9. row softmax over S (512 rows of 64) ----
__global__ void k_softmax(float* __restrict__ Sb) {
    int row = blockIdx.x;
    int s = threadIdx.x;
    float v = Sb[(size_t)row * LLH + s];
    float m = v;
    #pragma unroll
    for (int off = 32; off > 0; off >>= 1) m = fmaxf(m, __shfl_xor(m, off));
    float e = __expf(v - m);
    float sum = e;
    #pragma unroll
    for (int off = 32; off > 0; off >>= 1) sum += __shfl_xor(sum, off);
    Sb[(size_t)row * LLH + s] = e / sum;
}

// ---- 10. seq = attn @ v -> out [8, 64, 2048, 8] (flat == [8,64,16384]) ----
__global__ __launch_bounds__(256) void k_attnV(const float* __restrict__ Fl,
                                               const float* __restrict__ Sb,
                                               float* __restrict__ out) {
    int b = blockIdx.y;
    int d = blockIdx.x * 256 + threadIdx.x;
    __shared__ float a[64][65];
    for (int i = threadIdx.x; i < 64 * 64; i += 256) a[i >> 6][i & 63] = Sb[(size_t)b * LLH * LLH + i];
    __syncthreads();
    const float* vbase = Fl + (size_t)b * LLH * FDIM + DQ + d;        // v third
    float acc[64];
    #pragma unroll
    for (int t = 0; t < 64; ++t) acc[t] = 0.f;
    for (int s = 0; s < 64; ++s) {
        float vv = vbase[(size_t)s * FDIM];
        #pragma unroll
        for (int t = 0; t < 64; ++t) acc[t] += a[t][s] * vv;
    }
    float* ob = out + (size_t)b * LLH * DQ + d;
    #pragma unroll
    for (int t = 0; t < 64; ++t) ob[(size_t)t * DQ] = acc[t];
}

extern "C" void kernel_launch(void* const* d_in, const int* in_sizes, int n_in,
                              void* d_out, int out_size, void* d_ws, size_t ws_size,
                              hipStream_t stream) {
    (void)in_sizes; (void)n_in; (void)out_size; (void)ws_size;
    const float* latent = (const float*)d_in[0];
    const int*   ei     = (const int*)d_in[1];
    const float* Wd     = (const float*)d_in[2];
    const float* bd     = (const float*)d_in[3];
    const float* w1     = (const float*)d_in[4];
    const float* b1     = (const float*)d_in[5];
    const float* Wq     = (const float*)d_in[6];
    const float* bq     = (const float*)d_in[7];
    const float* Wk     = (const float*)d_in[8];
    const float* bk     = (const float*)d_in[9];
    const float* Wv     = (const float*)d_in[10];
    const float* gbias  = (const float*)d_in[11];
    const float* qw     = (const float*)d_in[12];
    const float* qb     = (const float*)d_in[13];
    float* out = (float*)d_out;

    float* ws   = (float*)d_ws;
    float* sk   = ws;                       // 16384
    float* xb   = sk + BNN;                 // 131072
    float* Qg   = xb + BNN * EE;            // 131072
    float* Kg   = Qg + BNN * EE;            // 131072
    float* Vg   = Kg + BNN * EE;            // 131072
    float* hg   = Vg + BNN * EE;            // 131072
    float* smax = hg + BNN * EE;            // 16384
    float* ssum = smax + BNN;               // 16384
    float* sc   = ssum + BNN;               // 540672
    float* Sb   = sc + ETOT;                // 32768
    float* Fl   = Sb + BSZ * LLH * LLH;     // 25165824  (~total 106 MB)

    k_dense<<<dim3(64), dim3(256), 0, stream>>>(latent, Wd, bd, sk);
    k_conv1<<<dim3(64), dim3(256), 0, stream>>>(sk, w1, b1, xb);
    k_gatqkv<<<dim3(64), dim3(256), 0, stream>>>(xb, Wq, bq, Wk, bk, Wv, gbias,
                                                 Qg, Kg, Vg, hg, smax, ssum, Sb);
    k_escore<<<dim3(ETOT / 256), dim3(256), 0, stream>>>(ei, Qg, Kg, sc, smax);
    k_eexp<<<dim3(ETOT / 256), dim3(256), 0, stream>>>(ei, smax, sc, ssum);
    k_eaggr<<<dim3(ETOT * EE / 256), dim3(256), 0, stream>>>(ei, sc, ssum, Vg, hg);
    k_qkvconv<<<dim3(6, 64, 8), dim3(256), 0, stream>>>(hg, qw, qb, Fl);
    k_attnS<<<dim3(64, 8), dim3(256), 0, stream>>>(Fl, Sb);
    k_softmax<<<dim3(512), dim3(64), 0, stream>>>(Sb);
    k_attnV<<<dim3(64, 8), dim3(256), 0, stream>>>(Fl, Sb, out);
}

// Round 3
// 245.828 us; speedup vs baseline: 1.0645x; 1.0645x over previous
//
#include <hip/hip_runtime.h>
#include <math.h>

#define BSZ 8
#define DDIM 512
#define NND 2048
#define EE 8
#define LLH 64
#define NEDGE 524288
#define BNN 16384          // BSZ*NND
#define ETOT 540672        // NEDGE + BNN
#define OCC 1536           // 3*EE*LLH
#define DQ 16384           // NND*EE (per-third d dimension)
#define NCHK 128           // attnS d-chunks
#define DCH 128            // attnS d per chunk

__device__ inline void atomicMaxF(float* addr, float v) {
    if (v >= 0.f) atomicMax((int*)addr, __float_as_int(v));
    else atomicMin((unsigned int*)addr, (unsigned int)__float_as_int(v));
}

// ---- 1. skeleton = latent @ W_dense + b_dense -> [8, 2048] ----
__global__ __launch_bounds__(256) void k_dense(const float* __restrict__ latent,
                                               const float* __restrict__ Wd,
                                               const float* __restrict__ bd,
                                               float* __restrict__ sk) {
    __shared__ float lat[BSZ * DDIM];   // 16 KB
    int tid = threadIdx.x;
    for (int i = tid; i < BSZ * DDIM; i += 256) lat[i] = latent[i];
    __syncthreads();
    int n = blockIdx.x * 32 + (tid & 31);
    int b = tid >> 5;
    float acc = 0.f;
    for (int d = 0; d < DDIM; ++d) acc += lat[b * DDIM + d] * Wd[d * NND + n];
    sk[b * NND + n] = acc + bd[n];
}

// ---- 2. conv1d(K=3, Cin=1, Cout=8, SAME) -> x [16384, 8] ----
__global__ void k_conv1(const float* __restrict__ sk, const float* __restrict__ w1,
                        const float* __restrict__ b1, float* __restrict__ xb) {
    int bn = blockIdx.x * 256 + threadIdx.x;
    if (bn >= BNN) return;
    int n = bn & (NND - 1);
    float sm = (n > 0) ? sk[bn - 1] : 0.f;
    float s0 = sk[bn];
    float sp = (n < NND - 1) ? sk[bn + 1] : 0.f;
    #pragma unroll
    for (int e = 0; e < EE; ++e)
        xb[bn * EE + e] = sm * w1[e] + s0 * w1[EE + e] + sp * w1[2 * EE + e] + b1[e];
}

// ---- 3. GAT Q/K/V projections + per-call init of reduction buffers ----
__global__ void k_gatqkv(const float* __restrict__ xb,
                         const float* __restrict__ Wq, const float* __restrict__ bq,
                         const float* __restrict__ Wk, const float* __restrict__ bk,
                         const float* __restrict__ Wv, const float* __restrict__ gbias,
                         float* __restrict__ Qg, float* __restrict__ Kg,
                         float* __restrict__ Vg, float* __restrict__ hg,
                         float* __restrict__ smax, float* __restrict__ ssum) {
    int i = blockIdx.x * 256 + threadIdx.x;
    if (i >= BNN) return;
    float xr[EE];
    #pragma unroll
    for (int c = 0; c < EE; ++c) xr[c] = xb[i * EE + c];
    #pragma unroll
    for (int j = 0; j < EE; ++j) {
        float q = bq[j], k = bk[j], v = 0.f;
        #pragma unroll
        for (int c = 0; c < EE; ++c) {
            q += xr[c] * Wq[c * EE + j];
            k += xr[c] * Wk[c * EE + j];
            v += xr[c] * Wv[c * EE + j];
        }
        Qg[i * EE + j] = (q >= 0.f) ? q : 0.2f * q;
        Kg[i * EE + j] = (k >= 0.f) ? k : 0.2f * k;
        Vg[i * EE + j] = v;
        hg[i * EE + j] = gbias[j];   // aggregate lands on top of bias
    }
    smax[i] = -INFINITY;
    ssum[i] = 0.f;
}

// ---- 4. edge scores + segment max ----
__global__ void k_escore(const int* __restrict__ ei, const float* __restrict__ Qg,
                         const float* __restrict__ Kg, float* __restrict__ sc,
                         float* __restrict__ smax) {
    int e = blockIdx.x * 256 + threadIdx.x;
    if (e >= ETOT) return;
    int r, c;
    if (e < NEDGE) { r = ei[e]; c = ei[NEDGE + e]; } else { r = c = e - NEDGE; }
    const float4* Q4 = (const float4*)(Qg + r * EE);
    const float4* K4 = (const float4*)(Kg + c * EE);
    float4 qa = Q4[0], qb2 = Q4[1], ka = K4[0], kb2 = K4[1];
    float s = qa.x * ka.x + qa.y * ka.y + qa.z * ka.z + qa.w * ka.w
            + qb2.x * kb2.x + qb2.y * kb2.y + qb2.z * kb2.z + qb2.w * kb2.w;
    sc[e] = s;
    atomicMaxF(smax + r, s);
}

// ---- 5. exp + segment sum ----
__global__ void k_eexp(const int* __restrict__ ei, const float* __restrict__ smax,
                       float* __restrict__ sc, float* __restrict__ ssum) {
    int e = blockIdx.x * 256 + threadIdx.x;
    if (e >= ETOT) return;
    int r = (e < NEDGE) ? ei[e] : e - NEDGE;
    float ex = __expf(sc[e] - smax[r]);
    sc[e] = ex;
    atomicAdd(ssum + r, ex);
}

// ---- 6. alpha * V scatter-aggregate ----
__global__ void k_eaggr(const int* __restrict__ ei, const float* __restrict__ sc,
                        const float* __restrict__ ssum, const float* __restrict__ Vg,
                        float* __restrict__ hg) {
    long long t = (long long)blockIdx.x * 256 + threadIdx.x;
    if (t >= (long long)ETOT * EE) return;
    int e = (int)(t >> 3), j = (int)(t & 7);
    int r, c;
    if (e < NEDGE) { r = ei[e]; c = ei[NEDGE + e]; } else { r = c = e - NEDGE; }
    float alpha = sc[e] / ssum[r];
    atomicAdd(hg + r * EE + j, alpha * Vg[c * EE + j]);
}

// ---- 7. qkv conv (K=3, Cin=8, Cout=1536) -> qT[b][d][t], Fv[b][s][d], kT[b][d][t] ----
// grid (128 n-chunks, 2 l-groups, 8 b); each block: 16 nodes x 32 l x 24 c
__global__ __launch_bounds__(256) void k_qkvconv(const float* __restrict__ hg,
                                                 const float* __restrict__ qw,
                                                 const float* __restrict__ qb,
                                                 float* __restrict__ qT,
                                                 float* __restrict__ Fv,
                                                 float* __restrict__ kT) {
    int nc = blockIdx.x, lg = blockIdx.y, b = blockIdx.z;
    int n0 = nc * 16, l0 = lg * 32;
    __shared__ float tile[32][385];   // [l][n_local*24+c], pad 385 -> 49.3 KB
    int tid = threadIdx.x;

    // each thread owns 3 output channels o = (l0+l)*24+c
    int ol0 = tid;                    // +256, +512
    float w[3][24], bias[3];
    #pragma unroll
    for (int rep = 0; rep < 3; ++rep) {
        int ol = ol0 + rep * 256;
        int o = l0 * 24 + ol;
        bias[rep] = qb[o];
        #pragma unroll
        for (int kk = 0; kk < 24; ++kk) w[rep][kk] = qw[kk * OCC + o];
    }
    for (int nn = 0; nn < 16; ++nn) {
        float hv[24];
        #pragma unroll
        for (int kk = 0; kk < 24; ++kk) {
            int nrow = n0 + nn - 1 + (kk >> 3);          // uniform across block
            hv[kk] = (nrow >= 0 && nrow < NND) ? hg[((size_t)b * NND + nrow) * EE + (kk & 7)] : 0.f;
        }
        #pragma unroll
        for (int rep = 0; rep < 3; ++rep) {
            int ol = ol0 + rep * 256;
            int l = ol / 24, c = ol - l * 24;
            float acc = bias[rep];
            #pragma unroll
            for (int kk = 0; kk < 24; ++kk) acc += hv[kk] * w[rep][kk];
            tile[l][nn * 24 + c] = acc;
        }
    }
    __syncthreads();

    int fbase = n0 * 24;   // block covers flat f in [fbase, fbase+384)
    bool hasQK = (fbase < DQ) || (fbase + 384 > 2 * DQ);
    bool hasV  = (fbase + 384 > DQ) && (fbase < 2 * DQ);
    if (hasQK) {
        for (int j = tid; j < 384 * 32; j += 256) {
            int l = j & 31, fo = j >> 5;
            int f = fbase + fo;
            float val = tile[l][fo];
            if (f < DQ)
                qT[((size_t)b * DQ + f) * LLH + l0 + l] = val;
            else if (f >= 2 * DQ)
                kT[((size_t)b * DQ + (f - 2 * DQ)) * LLH + l0 + l] = val;
        }
    }
    if (hasV) {
        for (int j = tid; j < 384 * 32; j += 256) {
            int fo = j % 384, l = j / 384 + (j % 384) * 0;   // l-major blocks of 384
            l = j / 384;
            int f = fbase + fo;
            if (f >= DQ && f < 2 * DQ)
                Fv[((size_t)b * LLH + l0 + l) * DQ + (f - DQ)] = tile[l][fo];
        }
    }
}

// ---- 8. S partials: Spart[ch][b][t][s] = sum_{d in chunk} q[t][d] k[s][d] ----
// grid (128, 8), block 256 = 4 waves(16 t each) x 64 lanes(s)
__global__ __launch_bounds__(256) void k_attnS(const float* __restrict__ qT,
                                               const float* __restrict__ kT,
                                               float* __restrict__ Spart) {
    int ch = blockIdx.x, b = blockIdx.y;
    int s = threadIdx.x & 63;
    int t0 = __builtin_amdgcn_readfirstlane((threadIdx.x >> 6) * 16);
    int d0 = ch * DCH;
    const float* kcol  = kT + ((size_t)b * DQ + d0) * LLH + s;
    const float* qbase = qT + ((size_t)b * DQ + d0) * LLH + t0;
    float acc[16];
    #pragma unroll
    for (int tt = 0; tt < 16; ++tt) acc[tt] = 0.f;
    #pragma unroll 4
    for (int d = 0; d < DCH; ++d) {
        float kv = kcol[(size_t)d * LLH];
        #pragma unroll
        for (int tt = 0; tt < 16; ++tt)
            acc[tt] += qbase[d * LLH + tt] * kv;     // q reads are wave-uniform -> s_load
    }
    float* part = Spart + (((size_t)ch * BSZ + b) * LLH + t0) * LLH + s;
    #pragma unroll
    for (int tt = 0; tt < 16; ++tt) part[(size_t)tt * LLH] = acc[tt];
}

// ---- 9. row softmax over summed partials -> atT[b][s][t] (transposed) ----
__global__ void k_softmax(const float* __restrict__ Spart, float* __restrict__ atT) {
    int b = blockIdx.x >> 6, t = blockIdx.x & 63;
    int s = threadIdx.x;
    float v = 0.f;
    for (int ch = 0; ch < NCHK; ++ch)
        v += Spart[(((size_t)ch * BSZ + b) * LLH + t) * LLH + s];
    float m = v;
    #pragma unroll
    for (int off = 32; off > 0; off >>= 1) m = fmaxf(m, __shfl_xor(m, off));
    float e = __expf(v - m);
    float sum = e;
    #pragma unroll
    for (int off = 32; off > 0; off >>= 1) sum += __shfl_xor(sum, off);
    atT[((size_t)b * LLH + s) * LLH + t] = e / sum;
}

// ---- 10. out[b][t][d] = sum_s atT[b][s][t] * Fv[b][s][d] ----
// grid (256, 8), block 256 = 4 waves(16 t) x 64 lanes(d)
__global__ __launch_bounds__(256) void k_attnV(const float* __restrict__ Fv,
                                               const float* __restrict__ atT,
                                               float* __restrict__ out) {
    int b = blockIdx.y;
    int d = blockIdx.x * 64 + (threadIdx.x & 63);
    int t0 = __builtin_amdgcn_readfirstlane((threadIdx.x >> 6) * 16);
    const float* vcol = Fv + (size_t)b * LLH * DQ + d;
    const float* arow = atT + (size_t)b * LLH * LLH + t0;
    float acc[16];
    #pragma unroll
    for (int tt = 0; tt < 16; ++tt) acc[tt] = 0.f;
    #pragma unroll 4
    for (int s = 0; s < LLH; ++s) {
        float vv = vcol[(size_t)s * DQ];
        #pragma unroll
        for (int tt = 0; tt < 16; ++tt)
            acc[tt] += arow[s * LLH + tt] * vv;      // a reads are wave-uniform -> s_load
    }
    float* ob = out + ((size_t)b * LLH + t0) * DQ + d;
    #pragma unroll
    for (int tt = 0; tt < 16; ++tt) ob[(size_t)tt * DQ] = acc[tt];
}

extern "C" void kernel_launch(void* const* d_in, const int* in_sizes, int n_in,
                              void* d_out, int out_size, void* d_ws, size_t ws_size,
                              hipStream_t stream) {
    (void)in_sizes; (void)n_in; (void)out_size; (void)ws_size;
    const float* latent = (const float*)d_in[0];
    const int*   ei     = (const int*)d_in[1];
    const float* Wd     = (const float*)d_in[2];
    const float* bd     = (const float*)d_in[3];
    const float* w1     = (const float*)d_in[4];
    const float* b1     = (const float*)d_in[5];
    const float* Wq     = (const float*)d_in[6];
    const float* bq     = (const float*)d_in[7];
    const float* Wk     = (const float*)d_in[8];
    const float* bk     = (const float*)d_in[9];
    const float* Wv     = (const float*)d_in[10];
    const float* gbias  = (const float*)d_in[11];
    const float* qw     = (const float*)d_in[12];
    const float* qb     = (const float*)d_in[13];
    float* out = (float*)d_out;

    float* ws   = (float*)d_ws;
    float* sk   = ws;                        // 16384
    float* xb   = sk + BNN;                  // 131072
    float* Qg   = xb + BNN * EE;             // 131072
    float* Kg   = Qg + BNN * EE;             // 131072
    float* Vg   = Kg + BNN * EE;             // 131072
    float* hg   = Vg + BNN * EE;             // 131072
    float* smax = hg + BNN * EE;             // 16384
    float* ssum = smax + BNN;                // 16384
    float* sc   = ssum + BNN;                // 540672
    float* Spart= sc + ETOT;                 // 128*8*64*64 = 4194304
    float* atT  = Spart + (size_t)NCHK * BSZ * LLH * LLH;  // 32768
    float* qT   = atT + BSZ * LLH * LLH;     // 8388608
    float* Fv   = qT + (size_t)BSZ * DQ * LLH;             // 8388608
    float* kT   = Fv + (size_t)BSZ * DQ * LLH;             // 8388608
    // total ~30.6M floats = ~123 MB

    k_dense<<<dim3(64), dim3(256), 0, stream>>>(latent, Wd, bd, sk);
    k_conv1<<<dim3(64), dim3(256), 0, stream>>>(sk, w1, b1, xb);
    k_gatqkv<<<dim3(64), dim3(256), 0, stream>>>(xb, Wq, bq, Wk, bk, Wv, gbias,
                                                 Qg, Kg, Vg, hg, smax, ssum);
    k_escore<<<dim3(ETOT / 256), dim3(256), 0, stream>>>(ei, Qg, Kg, sc, smax);
    k_eexp<<<dim3(ETOT / 256), dim3(256), 0, stream>>>(ei, smax, sc, ssum);
    k_eaggr<<<dim3(ETOT * EE / 256), dim3(256), 0, stream>>>(ei, sc, ssum, Vg, hg);
    k_qkvconv<<<dim3(128, 2, 8), dim3(256), 0, stream>>>(hg, qw, qb, qT, Fv, kT);
    k_attnS<<<dim3(NCHK, 8), dim3(256), 0, stream>>>(qT, kT, Spart);
    k_softmax<<<dim3(512), dim3(64), 0, stream>>>(Spart, atT);
    k_attnV<<<dim3(256, 8), dim3(256), 0, stream>>>(Fv, atT, out);
}